// Round 4
// baseline (550.067 us; speedup 1.0000x reference)
//
#include <hip/hip_runtime.h>
#include <hip/hip_bf16.h>

typedef short v8s __attribute__((ext_vector_type(8)));
typedef float v4f __attribute__((ext_vector_type(4)));
typedef unsigned int v4u __attribute__((ext_vector_type(4)));
typedef unsigned int v2u __attribute__((ext_vector_type(2)));

#define DEV static __device__ __forceinline__

DEV float bf2f(unsigned short u){ unsigned int x=((unsigned int)u)<<16; float f; __builtin_memcpy(&f,&x,4); return f; }
DEV short f2bf(float f){ __hip_bfloat16 h=__float2bfloat16(f); short s; __builtin_memcpy(&s,&h,2); return s; }
// fp32 -> bf16 round-to-nearest-even, as low 16 bits of a u32 (finite inputs)
DEV unsigned int f2bfu(float f){ unsigned int u; __builtin_memcpy(&u,&f,4); return (u + 0x7fffu + ((u>>16)&1u)) >> 16; }
DEV v4f mfma16(v8s a, v8s b, v4f c){ return __builtin_amdgcn_mfma_f32_16x16x32_bf16(a,b,c,0,0,0); }

DEV float redmax16(float v){
  v=fmaxf(v,__shfl_xor(v,1)); v=fmaxf(v,__shfl_xor(v,2));
  v=fmaxf(v,__shfl_xor(v,4)); v=fmaxf(v,__shfl_xor(v,8)); return v;
}
DEV float redsum16(float v){
  v+=__shfl_xor(v,1); v+=__shfl_xor(v,2); v+=__shfl_xor(v,4); v+=__shfl_xor(v,8); return v;
}

// ---------------- fp32 -> bf16 pre-conversion (x, Wq, Wk, Wv) ----------------
// 1,835,008 groups of 4 elems: [0,1048576)=x, then 262144 each for Wq,Wk,Wv.
__global__ __launch_bounds__(256) void convert_kernel(
    const float* __restrict__ x,  const float* __restrict__ Wq,
    const float* __restrict__ Wk, const float* __restrict__ Wv,
    short* __restrict__ xb, short* __restrict__ wqb,
    short* __restrict__ wkb, short* __restrict__ wvb)
{
  unsigned g = blockIdx.x*256u + threadIdx.x;
  const float* src; short* dst; unsigned off;
  if (g < 1048576u){ src=x;  dst=xb;  off=g; }
  else if (g < 1310720u){ src=Wq; dst=wqb; off=g-1048576u; }
  else if (g < 1572864u){ src=Wk; dst=wkb; off=g-1310720u; }
  else { src=Wv; dst=wvb; off=g-1572864u; }
  v4f f = *(const v4f*)(src + (size_t)off*4);
  unsigned lo = f2bfu(f[0]) | (f2bfu(f[1])<<16);
  unsigned hi = f2bfu(f[2]) | (f2bfu(f[3])<<16);
  v2u r; r[0]=lo; r[1]=hi;
  *(v2u*)(dst + (size_t)off*4) = r;
}

// ---------------- shared 128x128 GEMM core (A bf16 [M][1024]; B bf16 or fp32 [N][1024]) ----
// LDS layout: [row][slot 0..3] of 16B, physical slot = logical ^ ((row>>1)&3)
template<int BF32>
DEV void gemm_core(const short* __restrict__ A, const void* __restrict__ Bmat,
                   int brow0, int bn0, int tid, short* As, short* Bs, v4f acc[4][4])
{
  const int l = tid & 63, w = tid >> 6;
  const int wr = (w>>1)*64, wc = (w&1)*64;
  const short* B16 = (const short*)Bmat;
  const float* B32 = (const float*)Bmat;
  for (int kt=0; kt<32; ++kt){
    v4u ra0, ra1, rb0, rb1;
    {
      int idx=tid;      int row=idx>>2, p=idx&3;
      ra0 = *(const v4u*)(A + (size_t)(brow0+row)*1024 + kt*32 + (p^((row>>1)&3))*8);
      idx=tid+256;      row=idx>>2; p=idx&3;
      ra1 = *(const v4u*)(A + (size_t)(brow0+row)*1024 + kt*32 + (p^((row>>1)&3))*8);
      if (BF32){
        idx=tid;        row=idx>>2; p=idx&3;
        {
          const float* s0 = B32 + (size_t)(bn0+row)*1024 + kt*32 + (p^((row>>1)&3))*8;
          v4f f0=*(const v4f*)s0, f1=*(const v4f*)(s0+4);
          rb0[0]=f2bfu(f0[0])|(f2bfu(f0[1])<<16); rb0[1]=f2bfu(f0[2])|(f2bfu(f0[3])<<16);
          rb0[2]=f2bfu(f1[0])|(f2bfu(f1[1])<<16); rb0[3]=f2bfu(f1[2])|(f2bfu(f1[3])<<16);
        }
        idx=tid+256;    row=idx>>2; p=idx&3;
        {
          const float* s1 = B32 + (size_t)(bn0+row)*1024 + kt*32 + (p^((row>>1)&3))*8;
          v4f f0=*(const v4f*)s1, f1=*(const v4f*)(s1+4);
          rb1[0]=f2bfu(f0[0])|(f2bfu(f0[1])<<16); rb1[1]=f2bfu(f0[2])|(f2bfu(f0[3])<<16);
          rb1[2]=f2bfu(f1[0])|(f2bfu(f1[1])<<16); rb1[3]=f2bfu(f1[2])|(f2bfu(f1[3])<<16);
        }
      } else {
        int idx2=tid;   int row=idx2>>2, p=idx2&3;
        rb0 = *(const v4u*)(B16 + (size_t)(bn0+row)*1024 + kt*32 + (p^((row>>1)&3))*8);
        idx2=tid+256;   row=idx2>>2; p=idx2&3;
        rb1 = *(const v4u*)(B16 + (size_t)(bn0+row)*1024 + kt*32 + (p^((row>>1)&3))*8);
      }
    }
    __syncthreads();
    *(v4u*)&As[(size_t)tid*8]       = ra0;
    *(v4u*)&As[(size_t)(tid+256)*8] = ra1;
    *(v4u*)&Bs[(size_t)tid*8]       = rb0;
    *(v4u*)&Bs[(size_t)(tid+256)*8] = rb1;
    __syncthreads();
    v8s af[4], bfr[4];
    #pragma unroll
    for (int m=0;m<4;++m){ int r=wr+m*16+(l&15); af[m]=*(const v8s*)&As[(r*4+((l>>4)^((r>>1)&3)))*8]; }
    #pragma unroll
    for (int n=0;n<4;++n){ int r=wc+n*16+(l&15); bfr[n]=*(const v8s*)&Bs[(r*4+((l>>4)^((r>>1)&3)))*8]; }
    #pragma unroll
    for (int m=0;m<4;++m)
      #pragma unroll
      for (int n=0;n<4;++n)
        acc[m][n]=mfma16(af[m],bfr[n],acc[m][n]);
  }
}

// ---------------- fused QKV projection (all-bf16 operands, fp32 bias) ----------------
// grid (24, 32). Q,K written [bh][s][64]; V written in MFMA-B-fragment order:
//   read lane l elem j = V[key=c*32+(l>>4)*8+j][d=dt*16+(l&15)]
__global__ __launch_bounds__(256) void qkv_gemm(const short* __restrict__ xb,
    const short* __restrict__ wqb, const short* __restrict__ wkb, const short* __restrict__ wvb,
    const float* __restrict__ bq, const float* __restrict__ bk, const float* __restrict__ bv,
    short* __restrict__ qo, short* __restrict__ ko, short* __restrict__ vfo)
{
  __shared__ short As[4096], Bs[4096];
  const int tid=threadIdx.x, l=tid&63, w=tid>>6;
  const int bcol0=blockIdx.x*128, brow0=blockIdx.y*128;
  const int mat=bcol0>>10, n0=bcol0&1023;
  const short* Wm   = mat==0?wqb:(mat==1?wkb:wvb);
  const float* bias = mat==0?bq:(mat==1?bk:bv);
  v4f acc[4][4];
  v4f vz={0.f,0.f,0.f,0.f};
  #pragma unroll
  for(int m=0;m<4;++m)
    #pragma unroll
    for(int n=0;n<4;++n) acc[m][n]=vz;
  gemm_core<0>(xb, Wm, brow0, n0, tid, As, Bs, acc);
  const int wr=(w>>1)*64, wc=(w&1)*64;
  #pragma unroll
  for(int m=0;m<4;++m)
  #pragma unroll
  for(int n=0;n<4;++n)
  #pragma unroll
  for(int r=0;r<4;++r){
    int row=brow0+wr+m*16+(l>>4)*4+r;       // 0..4095  (b*2048+s)
    int col=n0+wc+n*16+(l&15);              // 0..1023 within mat
    float v=acc[m][n][r]+bias[col];
    int b=row>>11, s=row&2047, h=col>>6, dk=col&63;
    int bh=b*16+h;
    short sv=f2bf(v);
    if(mat==0)      qo[((size_t)bh*2048+s)*64+dk]=sv;
    else if(mat==1) ko[((size_t)bh*2048+s)*64+dk]=sv;
    else{
      int kb=s>>9, c=(s>>5)&15, ki=s&31;
      int lane2=(ki>>3)*16+(dk&15);
      vfo[((((size_t)bh*4+kb)*16+c)*4+(size_t)(dk>>4))*512 + lane2*8 + (ki&7)]=sv;
    }
  }
}

// ---------------- total V column sums per bh (fp32) ----------------
__global__ __launch_bounds__(64) void vbsum_kernel(const short* __restrict__ vf, float* __restrict__ vb)
{
  const int bh=blockIdx.x, l=threadIdx.x;
  const short* base = vf + (size_t)bh*4*16*4*512;
  float acc[4]={0.f,0.f,0.f,0.f};
  for(int kb=0;kb<4;++kb)
    #pragma unroll
    for(int c=0;c<16;++c)
      #pragma unroll
      for(int dt=0;dt<4;++dt){
        v8s vv=*(const v8s*)(base + ((size_t)((kb*16+c)*4+dt))*512 + l*8);
        float s=0.f;
        #pragma unroll
        for(int j=0;j<8;++j) s+=bf2f((unsigned short)vv[j]);
        acc[dt]+=s;
      }
  #pragma unroll
  for(int dt=0;dt<4;++dt){
    acc[dt]+=__shfl_xor(acc[dt],16);
    acc[dt]+=__shfl_xor(acc[dt],32);
  }
  if(l<16){
    #pragma unroll
    for(int dt=0;dt<4;++dt) vb[(size_t)bh*64 + dt*16 + l]=acc[dt];
  }
}

// ---------------- fused double-softmax attention ----------------
// out_row = (Vsum_total + sum_{kb<=qb} (exp(p1)-1) V) / (2048 + sum (exp(p1)-1))
__global__ __launch_bounds__(256) void attn_kernel(
  const short* __restrict__ q, const short* __restrict__ k, const short* __restrict__ vf,
  const float* __restrict__ vbsum, short* __restrict__ attn)
{
  __shared__ short kbuf[256*64];      // 32KB: half key-block, XOR-swizzled 16B slots
  __shared__ short wbuf[4*16*40];     // per-wave P relayout buffer
  const int tid=threadIdx.x, l=tid&63, wv=tid>>6;
  const int qt=blockIdx.x, bh=blockIdx.y;
  const int qb=qt>>3;
  const int qrow0=qt*64+wv*16;
  const int b=bh>>4, h=bh&15;

  const short* qbase = q + (size_t)bh*2048*64;
  const short* kbase = k + (size_t)bh*2048*64;

  const short* qp = qbase + (size_t)(qrow0+(l&15))*64 + (l>>4)*8;
  v8s qa0=*(const v8s*)qp, qa1=*(const v8s*)(qp+32);

  v4f o[4]; v4f vz={0.f,0.f,0.f,0.f};
  #pragma unroll
  for(int dt=0;dt<4;++dt) o[dt]=vz;
  float zacc[4]={0.f,0.f,0.f,0.f};

  for (int kb=0; kb<=qb; ++kb){
    v4f sc[32];
    #pragma unroll
    for (int hb=0; hb<2; ++hb){
      __syncthreads();
      #pragma unroll
      for (int i=0;i<8;++i){
        int idx=i*256+tid; int key=idx>>3, p=idx&7, pp=p^(key&7);
        v4u val=*(const v4u*)(kbase + (size_t)(kb*512+hb*256+key)*64 + pp*8);
        *(v4u*)&kbuf[(key*8+p)*8] = val;
      }
      __syncthreads();
      #pragma unroll
      for (int t2=0;t2<16;++t2){
        int krow = t2*16 + (l&15);
        int s0 = ((l>>4)  ) ^ (krow&7);
        int s1 = ((l>>4)+4) ^ (krow&7);
        v8s k0=*(const v8s*)&kbuf[(krow*8+s0)*8];
        v8s k1=*(const v8s*)&kbuf[(krow*8+s1)*8];
        v4f t=mfma16(qa0,k0,vz);
        sc[hb*16+t2]=mfma16(qa1,k1,t);
      }
    }
    // scale + causal mask (diag block only) + first (block) softmax
    const bool diag = (kb==qb);
    float m1[4]={-3e38f,-3e38f,-3e38f,-3e38f};
    #pragma unroll
    for (int ct=0;ct<32;++ct){
      #pragma unroll
      for (int r=0;r<4;++r){
        float s=sc[ct][r]*0.125f;
        if (diag){
          int col=kb*512+ct*16+(l&15);
          int rowi=qrow0+(l>>4)*4+r;
          if (col>rowi) s=-1e30f;
        }
        sc[ct][r]=s;
        m1[r]=fmaxf(m1[r],s);
      }
    }
    float d1[4];
    #pragma unroll
    for (int r=0;r<4;++r) m1[r]=redmax16(m1[r]);
    #pragma unroll
    for (int r=0;r<4;++r) d1[r]=0.f;
    #pragma unroll
    for (int ct=0;ct<32;++ct)
      #pragma unroll
      for (int r=0;r<4;++r){
        float e=__expf(sc[ct][r]-m1[r]);
        sc[ct][r]=e;
        d1[r]+=e;
      }
    #pragma unroll
    for (int r=0;r<4;++r) d1[r]=1.0f/redsum16(d1[r]);   // inverse denom
    // PV: per 32-key chunk, w = exp(p1)-1 (exact 0 at masked positions)
    #pragma unroll
    for (int c=0;c<16;++c){
      #pragma unroll
      for (int p=0;p<2;++p){
        int ct=2*c+p;
        #pragma unroll
        for (int r=0;r<4;++r){
          float wgt=__expf(sc[ct][r]*d1[r])-1.0f;
          zacc[r]+=wgt;
          wbuf[wv*640 + ((l>>4)*4+r)*40 + p*16 + (l&15)] = f2bf(wgt);
        }
      }
      // cross-lane LDS exchange within the wave: fence both sides so the
      // loop-invariant-address read can't be hoisted above the writes.
      asm volatile("s_waitcnt lgkmcnt(0)" ::: "memory");
      v8s wa=*(const v8s*)&wbuf[wv*640 + (l&15)*40 + (l>>4)*8];
      asm volatile("" ::: "memory");
      const short* vfp = vf + ((((size_t)bh*4+kb)*16+c)*4)*512 + l*8;
      #pragma unroll
      for (int dt=0;dt<4;++dt){
        v8s vfr=*(const v8s*)(vfp + (size_t)dt*512);
        o[dt]=mfma16(wa,vfr,o[dt]);
      }
    }
  }
  // numerator baseline = total V sum (weight 1 for every key); Z baseline = 2048
  #pragma unroll
  for (int r=0;r<4;++r){
    float zz=2048.0f+redsum16(zacc[r]);
    float inv=1.0f/zz;
    int rowi=qrow0+(l>>4)*4+r;
    size_t obase=((size_t)b*2048+rowi)*1024 + h*64;
    #pragma unroll
    for (int dt=0;dt<4;++dt){
      float base=vbsum[(size_t)bh*64 + dt*16 + (l&15)];
      attn[obase + dt*16 + (l&15)] = f2bf((o[dt][r]+base)*inv);
    }
  }
}

// ---------------- output projection (A bf16, B fp32 on-the-fly, out fp32) ----------------
__global__ __launch_bounds__(256) void oproj_gemm(const short* __restrict__ at,
    const float* __restrict__ Wo, const float* __restrict__ bo, float* __restrict__ out)
{
  __shared__ short As[4096], Bs[4096];
  const int tid=threadIdx.x, l=tid&63, w=tid>>6;
  const int bcol0=blockIdx.x*128, brow0=blockIdx.y*128;
  v4f acc[4][4];
  v4f vz={0.f,0.f,0.f,0.f};
  #pragma unroll
  for(int m=0;m<4;++m)
    #pragma unroll
    for(int n=0;n<4;++n) acc[m][n]=vz;
  gemm_core<1>(at, Wo, brow0, bcol0, tid, As, Bs, acc);
  const int wr=(w>>1)*64, wc=(w&1)*64;
  #pragma unroll
  for(int m=0;m<4;++m)
  #pragma unroll
  for(int n=0;n<4;++n)
  #pragma unroll
  for(int r=0;r<4;++r){
    int row=brow0+wr+m*16+(l>>4)*4+r;
    int col=bcol0+wc+n*16+(l&15);
    out[(size_t)row*1024+col]=acc[m][n][r]+bo[col];
  }
}

extern "C" void kernel_launch(void* const* d_in, const int* in_sizes, int n_in,
                              void* d_out, int out_size, void* d_ws, size_t ws_size,
                              hipStream_t stream)
{
  const float* x  =(const float*)d_in[0];
  const float* Wq =(const float*)d_in[1];
  const float* bq =(const float*)d_in[2];
  const float* Wk =(const float*)d_in[3];
  const float* bk =(const float*)d_in[4];
  const float* Wv =(const float*)d_in[5];
  const float* bv =(const float*)d_in[6];
  const float* Wo =(const float*)d_in[7];
  const float* bo =(const float*)d_in[8];
  float* out=(float*)d_out;
  char* ws=(char*)d_ws;
  // ws (32 MiB): [0,8M)=xb then at_ws (disjoint lifetimes); [8M)=q; [16M)=k; [24M)=vf.
  // d_out (16 MB fp32) doubles as scratch until oproj overwrites it:
  //   [0,2M)=wqb, [2M,4M)=wkb, [4M,6M)=wvb (bf16), [7M)=vb (fp32 V-sums).
  short* xb_ws =(short*)(ws);
  short* at_ws =(short*)(ws);
  short* q_ws  =(short*)(ws + ((size_t)8<<20));
  short* k_ws  =(short*)(ws + ((size_t)16<<20));
  short* vf_ws =(short*)(ws + ((size_t)24<<20));
  char*  outb  =(char*)d_out;
  short* wqb   =(short*)(outb);
  short* wkb   =(short*)(outb + ((size_t)2<<20));
  short* wvb   =(short*)(outb + ((size_t)4<<20));
  float* vb_ws =(float*)(outb + ((size_t)7<<20));

  convert_kernel<<<dim3(7168),256,0,stream>>>(x,Wq,Wk,Wv,xb_ws,wqb,wkb,wvb);
  qkv_gemm<<<dim3(24,32),256,0,stream>>>(xb_ws,wqb,wkb,wvb,bq,bk,bv,q_ws,k_ws,vf_ws);
  vbsum_kernel<<<dim3(32),64,0,stream>>>(vf_ws,vb_ws);
  attn_kernel<<<dim3(32,32),256,0,stream>>>(q_ws,k_ws,vf_ws,vb_ws,at_ws);
  oproj_gemm<<<dim3(8,32),256,0,stream>>>(at_ws,Wo,bo,out);
}

// Round 5
// 248.405 us; speedup vs baseline: 2.2144x; 2.2144x over previous
//
#include <hip/hip_runtime.h>
#include <hip/hip_bf16.h>

typedef short v8s __attribute__((ext_vector_type(8)));
typedef float v4f __attribute__((ext_vector_type(4)));
typedef unsigned int v4u __attribute__((ext_vector_type(4)));
typedef unsigned int v2u __attribute__((ext_vector_type(2)));

#define DEV static __device__ __forceinline__

DEV float bf2f(unsigned short u){ unsigned int x=((unsigned int)u)<<16; float f; __builtin_memcpy(&f,&x,4); return f; }
DEV short f2bf(float f){ __hip_bfloat16 h=__float2bfloat16(f); short s; __builtin_memcpy(&s,&h,2); return s; }
// fp32 -> bf16 RTNE as low 16 bits of u32 (finite inputs)
DEV unsigned int f2bfu(float f){ unsigned int u; __builtin_memcpy(&u,&f,4); return (u + 0x7fffu + ((u>>16)&1u)) >> 16; }
DEV unsigned int pk2(float a, float b){ return f2bfu(a) | (f2bfu(b)<<16); }
DEV v4f mfma16(v8s a, v8s b, v4f c){ return __builtin_amdgcn_mfma_f32_16x16x32_bf16(a,b,c,0,0,0); }

// ---------------- fp32 -> bf16 pre-conversion (x, Wq, Wk, Wv) ----------------
__global__ __launch_bounds__(256) void convert_kernel(
    const float* __restrict__ x,  const float* __restrict__ Wq,
    const float* __restrict__ Wk, const float* __restrict__ Wv,
    short* __restrict__ xb, short* __restrict__ wqb,
    short* __restrict__ wkb, short* __restrict__ wvb)
{
  unsigned g = blockIdx.x*256u + threadIdx.x;
  const float* src; short* dst; unsigned off;
  if (g < 1048576u){ src=x;  dst=xb;  off=g; }
  else if (g < 1310720u){ src=Wq; dst=wqb; off=g-1048576u; }
  else if (g < 1572864u){ src=Wk; dst=wkb; off=g-1310720u; }
  else { src=Wv; dst=wvb; off=g-1572864u; }
  v4f f = *(const v4f*)(src + (size_t)off*4);
  v2u r; r[0]=pk2(f[0],f[1]); r[1]=pk2(f[2],f[3]);
  *(v2u*)(dst + (size_t)off*4) = r;
}

// ---------------- shared 128x128 GEMM core (A bf16 [M][1024]; B bf16 or fp32 [N][1024]) ----
template<int BF32>
DEV void gemm_core(const short* __restrict__ A, const void* __restrict__ Bmat,
                   int brow0, int bn0, int tid, short* As, short* Bs, v4f acc[4][4])
{
  const int l = tid & 63, w = tid >> 6;
  const int wr = (w>>1)*64, wc = (w&1)*64;
  const short* B16 = (const short*)Bmat;
  const float* B32 = (const float*)Bmat;
  for (int kt=0; kt<32; ++kt){
    v4u ra0, ra1, rb0, rb1;
    {
      int idx=tid;      int row=idx>>2, p=idx&3;
      ra0 = *(const v4u*)(A + (size_t)(brow0+row)*1024 + kt*32 + (p^((row>>1)&3))*8);
      idx=tid+256;      row=idx>>2; p=idx&3;
      ra1 = *(const v4u*)(A + (size_t)(brow0+row)*1024 + kt*32 + (p^((row>>1)&3))*8);
      if (BF32){
        idx=tid;        row=idx>>2; p=idx&3;
        {
          const float* s0 = B32 + (size_t)(bn0+row)*1024 + kt*32 + (p^((row>>1)&3))*8;
          v4f f0=*(const v4f*)s0, f1=*(const v4f*)(s0+4);
          rb0[0]=pk2(f0[0],f0[1]); rb0[1]=pk2(f0[2],f0[3]);
          rb0[2]=pk2(f1[0],f1[1]); rb0[3]=pk2(f1[2],f1[3]);
        }
        idx=tid+256;    row=idx>>2; p=idx&3;
        {
          const float* s1 = B32 + (size_t)(bn0+row)*1024 + kt*32 + (p^((row>>1)&3))*8;
          v4f f0=*(const v4f*)s1, f1=*(const v4f*)(s1+4);
          rb1[0]=pk2(f0[0],f0[1]); rb1[1]=pk2(f0[2],f0[3]);
          rb1[2]=pk2(f1[0],f1[1]); rb1[3]=pk2(f1[2],f1[3]);
        }
      } else {
        int idx2=tid;   int row=idx2>>2, p=idx2&3;
        rb0 = *(const v4u*)(B16 + (size_t)(bn0+row)*1024 + kt*32 + (p^((row>>1)&3))*8);
        idx2=tid+256;   row=idx2>>2; p=idx2&3;
        rb1 = *(const v4u*)(B16 + (size_t)(bn0+row)*1024 + kt*32 + (p^((row>>1)&3))*8);
      }
    }
    __syncthreads();
    *(v4u*)&As[(size_t)tid*8]       = ra0;
    *(v4u*)&As[(size_t)(tid+256)*8] = ra1;
    *(v4u*)&Bs[(size_t)tid*8]       = rb0;
    *(v4u*)&Bs[(size_t)(tid+256)*8] = rb1;
    __syncthreads();
    v8s af[4], bfr[4];
    #pragma unroll
    for (int m=0;m<4;++m){ int r=wr+m*16+(l&15); af[m]=*(const v8s*)&As[(r*4+((l>>4)^((r>>1)&3)))*8]; }
    #pragma unroll
    for (int n=0;n<4;++n){ int r=wc+n*16+(l&15); bfr[n]=*(const v8s*)&Bs[(r*4+((l>>4)^((r>>1)&3)))*8]; }
    #pragma unroll
    for (int m=0;m<4;++m)
      #pragma unroll
      for (int n=0;n<4;++n)
        acc[m][n]=mfma16(af[m],bfr[n],acc[m][n]);
  }
}

// ---------------- fused QKV projection ----------------
__global__ __launch_bounds__(256) void qkv_gemm(const short* __restrict__ xb,
    const short* __restrict__ wqb, const short* __restrict__ wkb, const short* __restrict__ wvb,
    const float* __restrict__ bq, const float* __restrict__ bk, const float* __restrict__ bv,
    short* __restrict__ qo, short* __restrict__ ko, short* __restrict__ vfo)
{
  __shared__ short As[4096], Bs[4096];
  const int tid=threadIdx.x, l=tid&63, w=tid>>6;
  const int bcol0=blockIdx.x*128, brow0=blockIdx.y*128;
  const int mat=bcol0>>10, n0=bcol0&1023;
  const short* Wm   = mat==0?wqb:(mat==1?wkb:wvb);
  const float* bias = mat==0?bq:(mat==1?bk:bv);
  v4f acc[4][4];
  v4f vz={0.f,0.f,0.f,0.f};
  #pragma unroll
  for(int m=0;m<4;++m)
    #pragma unroll
    for(int n=0;n<4;++n) acc[m][n]=vz;
  gemm_core<0>(xb, Wm, brow0, n0, tid, As, Bs, acc);
  const int wr=(w>>1)*64, wc=(w&1)*64;
  #pragma unroll
  for(int m=0;m<4;++m)
  #pragma unroll
  for(int n=0;n<4;++n)
  #pragma unroll
  for(int r=0;r<4;++r){
    int row=brow0+wr+m*16+(l>>4)*4+r;       // 0..4095  (b*2048+s)
    int col=n0+wc+n*16+(l&15);              // 0..1023 within mat
    float v=acc[m][n][r]+bias[col];
    int b=row>>11, s=row&2047, h=col>>6, dk=col&63;
    int bh=b*16+h;
    short sv=f2bf(v);
    if(mat==0)      qo[((size_t)bh*2048+s)*64+dk]=sv;
    else if(mat==1) ko[((size_t)bh*2048+s)*64+dk]=sv;
    else{
      int kb=s>>9, c=(s>>5)&15, ki=s&31;
      int lane2=(ki>>3)*16+(dk&15);
      vfo[((((size_t)bh*4+kb)*16+c)*4+(size_t)(dk>>4))*512 + lane2*8 + (ki&7)]=sv;
    }
  }
}

// ---------------- per-(bh,kb) V column sums (fp32 partials) ----------------
// grid (32,4): vbp[(bh*4+kb)*64 + d] = sum over that kb's 512 keys of V[key][d]
__global__ __launch_bounds__(64) void vbsum_kernel(const short* __restrict__ vf, float* __restrict__ vbp)
{
  const int bh=blockIdx.x, kb=blockIdx.y, l=threadIdx.x;
  const short* base = vf + ((size_t)(bh*4+kb))*16*4*512;
  float acc[4]={0.f,0.f,0.f,0.f};
  #pragma unroll
  for(int c=0;c<16;++c)
    #pragma unroll
    for(int dt=0;dt<4;++dt){
      v8s vv=*(const v8s*)(base + ((size_t)(c*4+dt))*512 + l*8);
      float s=0.f;
      #pragma unroll
      for(int j=0;j<8;++j) s+=bf2f((unsigned short)vv[j]);
      acc[dt]+=s;
    }
  #pragma unroll
  for(int dt=0;dt<4;++dt){
    acc[dt]+=__shfl_xor(acc[dt],16);
    acc[dt]+=__shfl_xor(acc[dt],32);
  }
  if(l<16){
    #pragma unroll
    for(int dt=0;dt<4;++dt) vbp[(size_t)(bh*4+kb)*64 + dt*16 + l]=acc[dt];
  }
}

// ---------------- fused double-softmax attention (swapped QK^T, register P-relayout) ------
// out_row = (Vsum_total + sum_{kb<=qb} (exp(p1)-1) V) / (2048 + sum (exp(p1)-1))
// Swapped: sc = mfma(K,Q) -> lane holds col = q-row (l&15), rows = keys (l>>4)*4+r per tile.
__global__ __launch_bounds__(256) void attn_kernel(
  const short* __restrict__ q, const short* __restrict__ k, const short* __restrict__ vf,
  const float* __restrict__ vbp, short* __restrict__ attn)
{
  __shared__ short kbuf[256*64];      // 32KB: half key-block, XOR-swizzled 16B slots, linear dest
  const int tid=threadIdx.x, l=tid&63, wv=tid>>6;
  const int bh=blockIdx.x, qt=31-blockIdx.y;   // heavy blocks (qb=3) dispatched first
  const int qb=qt>>3;
  const int qrow0=qt*64+wv*16;
  const int g=l>>4, q16=l&15;
  const int b=bh>>4, h=bh&15;
  const int qglob=qrow0+q16;

  const short* qbase = q + (size_t)bh*2048*64;
  const short* kbase = k + (size_t)bh*2048*64;

  const short* qp = qbase + (size_t)(qrow0+q16)*64 + g*8;
  v8s qa0=*(const v8s*)qp, qa1=*(const v8s*)(qp+32);

  v4f o[4]; v4f vz={0.f,0.f,0.f,0.f};
  #pragma unroll
  for(int dt=0;dt<4;++dt) o[dt]=vz;
  float zacc=0.f;

  for (int kb=0; kb<=qb; ++kb){
    v4f sc[32];
    #pragma unroll
    for (int hb=0; hb<2; ++hb){
      __syncthreads();
      #pragma unroll
      for (int i=0;i<8;++i){
        int idx=i*256+tid, key=idx>>3, p=idx&7, pp=p^(key&7);
        const short* gp = kbase + (size_t)(kb*512+hb*256+key)*64 + pp*8;
        __builtin_amdgcn_global_load_lds((const __attribute__((address_space(1))) void*)gp,
            (__attribute__((address_space(3))) void*)((char*)kbuf + idx*16), 16, 0, 0);
      }
      asm volatile("s_waitcnt vmcnt(0)" ::: "memory");
      __syncthreads();
      #pragma unroll
      for (int t2=0;t2<16;++t2){
        int krow = t2*16 + q16;
        int s0 = g ^ (krow&7);
        int s1 = (g+4) ^ (krow&7);
        v8s k0=*(const v8s*)&kbuf[(krow*8+s0)*8];
        v8s k1=*(const v8s*)&kbuf[(krow*8+s1)*8];
        v4f t=mfma16(k0,qa0,vz);           // SWAPPED: A=K, B=Q -> D[key][qrow]
        sc[hb*16+t2]=mfma16(k1,qa1,t);
      }
    }
    // scale + causal mask (diag block only) + first (block) softmax, all per-lane
    const bool diag = (kb==qb);
    float m1a[4]={-3e38f,-3e38f,-3e38f,-3e38f};
    #pragma unroll
    for (int ct=0;ct<32;++ct)
      #pragma unroll
      for (int r=0;r<4;++r){
        float s=sc[ct][r]*0.125f;
        if (diag && (qb*512+ct*16+g*4+r > qglob)) s=-1e38f;
        sc[ct][r]=s;
        m1a[r]=fmaxf(m1a[r],s);
      }
    float m1=fmaxf(fmaxf(m1a[0],m1a[1]),fmaxf(m1a[2],m1a[3]));
    m1=fmaxf(m1,__shfl_xor(m1,16)); m1=fmaxf(m1,__shfl_xor(m1,32));
    float d1a[4]={0.f,0.f,0.f,0.f};
    #pragma unroll
    for (int ct=0;ct<32;++ct)
      #pragma unroll
      for (int r=0;r<4;++r){
        float e=__expf(sc[ct][r]-m1);
        sc[ct][r]=e;
        d1a[r]+=e;
      }
    float d1=(d1a[0]+d1a[1])+(d1a[2]+d1a[3]);
    d1+=__shfl_xor(d1,16); d1+=__shfl_xor(d1,32);
    float d1inv=1.0f/d1;
    // PV: per 32-key chunk, w = exp(p1)-1; assemble A-fragment via register shuffles
    #pragma unroll
    for (int c=0;c<16;++c){
      float wA[4], wB[4];
      #pragma unroll
      for (int r=0;r<4;++r){
        wA[r]=__expf(sc[2*c  ][r]*d1inv)-1.0f;
        wB[r]=__expf(sc[2*c+1][r]*d1inv)-1.0f;
        zacc+=wA[r]+wB[r];
      }
      unsigned pA0=pk2(wA[0],wA[1]), pA1=pk2(wA[2],wA[3]);
      unsigned pB0=pk2(wB[0],wB[1]), pB1=pk2(wB[2],wB[3]);
      unsigned qA0=__shfl_xor(pA0,16), qA1=__shfl_xor(pA1,16);
      unsigned qB0=__shfl_xor(pB0,16), qB1=__shfl_xor(pB1,16);
      const bool godd=(g&1);
      unsigned FA0=godd?qA0:pA0, FA1=godd?qA1:pA1, FA2=godd?pA0:qA0, FA3=godd?pA1:qA1;
      unsigned FB0=godd?qB0:pB0, FB1=godd?qB1:pB1, FB2=godd?pB0:qB0, FB3=godd?pB1:qB1;
      unsigned S0=godd?FB0:FA0, S1=godd?FB1:FA1, S2=godd?FB2:FA2, S3=godd?FB3:FA3;
      unsigned R0=__shfl_xor(S0,48), R1=__shfl_xor(S1,48), R2=__shfl_xor(S2,48), R3=__shfl_xor(S3,48);
      union { v4u u; v8s s; } pa;
      pa.u[0]=(g==0)?FA0:(g==3)?FB0:R0;
      pa.u[1]=(g==0)?FA1:(g==3)?FB1:R1;
      pa.u[2]=(g==0)?FA2:(g==3)?FB2:R2;
      pa.u[3]=(g==0)?FA3:(g==3)?FB3:R3;
      const short* vfp = vf + ((((size_t)bh*4+kb)*16+c)*4)*512 + l*8;
      #pragma unroll
      for (int dt=0;dt<4;++dt){
        v8s vfr=*(const v8s*)(vfp + (size_t)dt*512);
        o[dt]=mfma16(pa.s,vfr,o[dt]);
      }
    }
  }
  // Z' for q-row q16 -> redistribute to output layout rows g*4+r
  float z=zacc;
  z+=__shfl_xor(z,16); z+=__shfl_xor(z,32);
  float base[4];
  #pragma unroll
  for (int dt=0;dt<4;++dt){
    float s=0.f;
    #pragma unroll
    for (int kk=0;kk<4;++kk) s+=vbp[(size_t)(bh*4+kk)*64 + dt*16 + q16];
    base[dt]=s;
  }
  #pragma unroll
  for (int r=0;r<4;++r){
    float zr=__shfl(z, g*4+r);
    float inv=1.0f/(2048.0f+zr);
    int rowi=qrow0+g*4+r;
    size_t obase=((size_t)b*2048+rowi)*1024 + h*64;
    #pragma unroll
    for (int dt=0;dt<4;++dt)
      attn[obase + dt*16 + q16] = f2bf((o[dt][r]+base[dt])*inv);
  }
}

// ---------------- output projection (A bf16, B fp32 on-the-fly, out fp32) ----------------
__global__ __launch_bounds__(256) void oproj_gemm(const short* __restrict__ at,
    const float* __restrict__ Wo, const float* __restrict__ bo, float* __restrict__ out)
{
  __shared__ short As[4096], Bs[4096];
  const int tid=threadIdx.x, l=tid&63, w=tid>>6;
  const int bcol0=blockIdx.x*128, brow0=blockIdx.y*128;
  v4f acc[4][4];
  v4f vz={0.f,0.f,0.f,0.f};
  #pragma unroll
  for(int m=0;m<4;++m)
    #pragma unroll
    for(int n=0;n<4;++n) acc[m][n]=vz;
  gemm_core<1>(at, Wo, brow0, bcol0, tid, As, Bs, acc);
  const int wr=(w>>1)*64, wc=(w&1)*64;
  #pragma unroll
  for(int m=0;m<4;++m)
  #pragma unroll
  for(int n=0;n<4;++n)
  #pragma unroll
  for(int r=0;r<4;++r){
    int row=brow0+wr+m*16+(l>>4)*4+r;
    int col=bcol0+wc+n*16+(l&15);
    out[(size_t)row*1024+col]=acc[m][n][r]+bo[col];
  }
}

extern "C" void kernel_launch(void* const* d_in, const int* in_sizes, int n_in,
                              void* d_out, int out_size, void* d_ws, size_t ws_size,
                              hipStream_t stream)
{
  const float* x  =(const float*)d_in[0];
  const float* Wq =(const float*)d_in[1];
  const float* bq =(const float*)d_in[2];
  const float* Wk =(const float*)d_in[3];
  const float* bk =(const float*)d_in[4];
  const float* Wv =(const float*)d_in[5];
  const float* bv =(const float*)d_in[6];
  const float* Wo =(const float*)d_in[7];
  const float* bo =(const float*)d_in[8];
  float* out=(float*)d_out;
  char* ws=(char*)d_ws;
  // ws (32 MiB): [0,8M)=xb then at_ws (disjoint lifetimes); [8M)=q; [16M)=k; [24M)=vf.
  // d_out doubles as scratch until oproj overwrites it:
  //   [0,2M)=wqb, [2M,4M)=wkb, [4M,6M)=wvb (bf16), [7M)=vbp (fp32, 32KB).
  short* xb_ws =(short*)(ws);
  short* at_ws =(short*)(ws);
  short* q_ws  =(short*)(ws + ((size_t)8<<20));
  short* k_ws  =(short*)(ws + ((size_t)16<<20));
  short* vf_ws =(short*)(ws + ((size_t)24<<20));
  char*  outb  =(char*)d_out;
  short* wqb   =(short*)(outb);
  short* wkb   =(short*)(outb + ((size_t)2<<20));
  short* wvb   =(short*)(outb + ((size_t)4<<20));
  float* vbp_ws=(float*)(outb + ((size_t)7<<20));

  convert_kernel<<<dim3(7168),256,0,stream>>>(x,Wq,Wk,Wv,xb_ws,wqb,wkb,wvb);
  qkv_gemm<<<dim3(24,32),256,0,stream>>>(xb_ws,wqb,wkb,wvb,bq,bk,bv,q_ws,k_ws,vf_ws);
  vbsum_kernel<<<dim3(32,4),64,0,stream>>>(vf_ws,vbp_ws);
  attn_kernel<<<dim3(32,32),256,0,stream>>>(q_ws,k_ws,vf_ws,vbp_ws,at_ws);
  oproj_gemm<<<dim3(8,32),256,0,stream>>>(at_ws,Wo,bo,out);
}

// Round 6
// 234.645 us; speedup vs baseline: 2.3443x; 1.0586x over previous
//
#include <hip/hip_runtime.h>
#include <hip/hip_bf16.h>

typedef short v8s __attribute__((ext_vector_type(8)));
typedef float v4f __attribute__((ext_vector_type(4)));
typedef unsigned int v4u __attribute__((ext_vector_type(4)));
typedef unsigned int v2u __attribute__((ext_vector_type(2)));

#define DEV static __device__ __forceinline__

DEV float bf2f(unsigned short u){ unsigned int x=((unsigned int)u)<<16; float f; __builtin_memcpy(&f,&x,4); return f; }
DEV short f2bf(float f){ __hip_bfloat16 h=__float2bfloat16(f); short s; __builtin_memcpy(&s,&h,2); return s; }
// fp32 -> bf16 RTNE as low 16 bits of u32 (finite inputs)
DEV unsigned int f2bfu(float f){ unsigned int u; __builtin_memcpy(&u,&f,4); return (u + 0x7fffu + ((u>>16)&1u)) >> 16; }
DEV unsigned int pk2(float a, float b){ return f2bfu(a) | (f2bfu(b)<<16); }
DEV v4f mfma16(v8s a, v8s b, v4f c){ return __builtin_amdgcn_mfma_f32_16x16x32_bf16(a,b,c,0,0,0); }

// ---------------- fp32 -> bf16 pre-conversion (x, Wq, Wk, Wv) ----------------
__global__ __launch_bounds__(256) void convert_kernel(
    const float* __restrict__ x,  const float* __restrict__ Wq,
    const float* __restrict__ Wk, const float* __restrict__ Wv,
    short* __restrict__ xb, short* __restrict__ wqb,
    short* __restrict__ wkb, short* __restrict__ wvb)
{
  unsigned g = blockIdx.x*256u + threadIdx.x;
  const float* src; short* dst; unsigned off;
  if (g < 1048576u){ src=x;  dst=xb;  off=g; }
  else if (g < 1310720u){ src=Wq; dst=wqb; off=g-1048576u; }
  else if (g < 1572864u){ src=Wk; dst=wkb; off=g-1310720u; }
  else { src=Wv; dst=wvb; off=g-1572864u; }
  v4f f = *(const v4f*)(src + (size_t)off*4);
  v2u r; r[0]=pk2(f[0],f[1]); r[1]=pk2(f[2],f[3]);
  *(v2u*)(dst + (size_t)off*4) = r;
}

// ---------------- shared 128x128 GEMM core (A bf16 [M][1024]; B bf16 or fp32 [N][1024]) ----
template<int BF32>
DEV void gemm_core(const short* __restrict__ A, const void* __restrict__ Bmat,
                   int brow0, int bn0, int tid, short* As, short* Bs, v4f acc[4][4])
{
  const int l = tid & 63, w = tid >> 6;
  const int wr = (w>>1)*64, wc = (w&1)*64;
  const short* B16 = (const short*)Bmat;
  const float* B32 = (const float*)Bmat;
  for (int kt=0; kt<32; ++kt){
    v4u ra0, ra1, rb0, rb1;
    {
      int idx=tid;      int row=idx>>2, p=idx&3;
      ra0 = *(const v4u*)(A + (size_t)(brow0+row)*1024 + kt*32 + (p^((row>>1)&3))*8);
      idx=tid+256;      row=idx>>2; p=idx&3;
      ra1 = *(const v4u*)(A + (size_t)(brow0+row)*1024 + kt*32 + (p^((row>>1)&3))*8);
      if (BF32){
        idx=tid;        row=idx>>2; p=idx&3;
        {
          const float* s0 = B32 + (size_t)(bn0+row)*1024 + kt*32 + (p^((row>>1)&3))*8;
          v4f f0=*(const v4f*)s0, f1=*(const v4f*)(s0+4);
          rb0[0]=pk2(f0[0],f0[1]); rb0[1]=pk2(f0[2],f0[3]);
          rb0[2]=pk2(f1[0],f1[1]); rb0[3]=pk2(f1[2],f1[3]);
        }
        idx=tid+256;    row=idx>>2; p=idx&3;
        {
          const float* s1 = B32 + (size_t)(bn0+row)*1024 + kt*32 + (p^((row>>1)&3))*8;
          v4f f0=*(const v4f*)s1, f1=*(const v4f*)(s1+4);
          rb1[0]=pk2(f0[0],f0[1]); rb1[1]=pk2(f0[2],f0[3]);
          rb1[2]=pk2(f1[0],f1[1]); rb1[3]=pk2(f1[2],f1[3]);
        }
      } else {
        int idx2=tid;   int row=idx2>>2, p=idx2&3;
        rb0 = *(const v4u*)(B16 + (size_t)(bn0+row)*1024 + kt*32 + (p^((row>>1)&3))*8);
        idx2=tid+256;   row=idx2>>2; p=idx2&3;
        rb1 = *(const v4u*)(B16 + (size_t)(bn0+row)*1024 + kt*32 + (p^((row>>1)&3))*8);
      }
    }
    __syncthreads();
    *(v4u*)&As[(size_t)tid*8]       = ra0;
    *(v4u*)&As[(size_t)(tid+256)*8] = ra1;
    *(v4u*)&Bs[(size_t)tid*8]       = rb0;
    *(v4u*)&Bs[(size_t)(tid+256)*8] = rb1;
    __syncthreads();
    v8s af[4], bfr[4];
    #pragma unroll
    for (int m=0;m<4;++m){ int r=wr+m*16+(l&15); af[m]=*(const v8s*)&As[(r*4+((l>>4)^((r>>1)&3)))*8]; }
    #pragma unroll
    for (int n=0;n<4;++n){ int r=wc+n*16+(l&15); bfr[n]=*(const v8s*)&Bs[(r*4+((l>>4)^((r>>1)&3)))*8]; }
    #pragma unroll
    for (int m=0;m<4;++m)
      #pragma unroll
      for (int n=0;n<4;++n)
        acc[m][n]=mfma16(af[m],bfr[n],acc[m][n]);
  }
}

// ---------------- fused QKV projection ----------------
// V stored PERMUTED within each 32-key chunk so attn's PV A-fragment needs no shuffles:
//   slot s = g2*8 + j maps key = (j<4 ? g2*4+j : 16+g2*4+(j-4)), g2 = (ki>>2)&3
__global__ __launch_bounds__(256) void qkv_gemm(const short* __restrict__ xb,
    const short* __restrict__ wqb, const short* __restrict__ wkb, const short* __restrict__ wvb,
    const float* __restrict__ bq, const float* __restrict__ bk, const float* __restrict__ bv,
    short* __restrict__ qo, short* __restrict__ ko, short* __restrict__ vfo)
{
  __shared__ short As[4096], Bs[4096];
  const int tid=threadIdx.x, l=tid&63, w=tid>>6;
  const int bcol0=blockIdx.x*128, brow0=blockIdx.y*128;
  const int mat=bcol0>>10, n0=bcol0&1023;
  const short* Wm   = mat==0?wqb:(mat==1?wkb:wvb);
  const float* bias = mat==0?bq:(mat==1?bk:bv);
  v4f acc[4][4];
  v4f vz={0.f,0.f,0.f,0.f};
  #pragma unroll
  for(int m=0;m<4;++m)
    #pragma unroll
    for(int n=0;n<4;++n) acc[m][n]=vz;
  gemm_core<0>(xb, Wm, brow0, n0, tid, As, Bs, acc);
  const int wr=(w>>1)*64, wc=(w&1)*64;
  #pragma unroll
  for(int m=0;m<4;++m)
  #pragma unroll
  for(int n=0;n<4;++n)
  #pragma unroll
  for(int r=0;r<4;++r){
    int row=brow0+wr+m*16+(l>>4)*4+r;       // 0..4095  (b*2048+s)
    int col=n0+wc+n*16+(l&15);              // 0..1023 within mat
    float v=acc[m][n][r]+bias[col];
    int b=row>>11, s=row&2047, h=col>>6, dk=col&63;
    int bh=b*16+h;
    short sv=f2bf(v);
    if(mat==0)      qo[((size_t)bh*2048+s)*64+dk]=sv;
    else if(mat==1) ko[((size_t)bh*2048+s)*64+dk]=sv;
    else{
      int kb=s>>9, c=(s>>5)&15, ki=s&31;
      int g2=(ki>>2)&3, j=(ki>>4)*4+(ki&3);
      int lane2=g2*16+(dk&15);
      vfo[((((size_t)bh*4+kb)*16+c)*4+(size_t)(dk>>4))*512 + lane2*8 + j]=sv;
    }
  }
}

// ---------------- per-(bh,kb) V column sums (fp32 partials) ----------------
// permutation-invariant: each lane's v8s holds 8 distinct keys at the same d
__global__ __launch_bounds__(64) void vbsum_kernel(const short* __restrict__ vf, float* __restrict__ vbp)
{
  const int bh=blockIdx.x, kb=blockIdx.y, l=threadIdx.x;
  const short* base = vf + ((size_t)(bh*4+kb))*16*4*512;
  float acc[4]={0.f,0.f,0.f,0.f};
  #pragma unroll
  for(int c=0;c<16;++c)
    #pragma unroll
    for(int dt=0;dt<4;++dt){
      v8s vv=*(const v8s*)(base + ((size_t)(c*4+dt))*512 + l*8);
      float s=0.f;
      #pragma unroll
      for(int j=0;j<8;++j) s+=bf2f((unsigned short)vv[j]);
      acc[dt]+=s;
    }
  #pragma unroll
  for(int dt=0;dt<4;++dt){
    acc[dt]+=__shfl_xor(acc[dt],16);
    acc[dt]+=__shfl_xor(acc[dt],32);
  }
  if(l<16){
    #pragma unroll
    for(int dt=0;dt<4;++dt) vbp[(size_t)(bh*4+kb)*64 + dt*16 + l]=acc[dt];
  }
}

// ---------------- fused double-softmax attention ----------------
// swapped QK^T (lane holds q-col, keys in regs) + permuted-V PV (no cross-lane relayout)
// + double-buffered K halves with counted vmcnt + raw s_barrier (prefetch stays in flight)
__global__ __launch_bounds__(256) void attn_kernel(
  const short* __restrict__ q, const short* __restrict__ k, const short* __restrict__ vf,
  const float* __restrict__ vbp, short* __restrict__ attn)
{
  __shared__ short kbuf[2*16384];     // 2 x 32KB half-blocks, XOR-swizzled 16B slots
  const int tid=threadIdx.x, l=tid&63, wv=tid>>6;
  const int bh=blockIdx.x, qt=31-blockIdx.y;   // heavy blocks (qb=3) first
  const int qb=qt>>3;
  const int qrow0=qt*64+wv*16;
  const int g=l>>4, q16=l&15;
  const int b=bh>>4, h=bh&15;
  const int qglob=qrow0+q16;

  const short* qbase = q + (size_t)bh*2048*64;
  const short* kbase = k + (size_t)bh*2048*64;

  const short* qp = qbase + (size_t)(qrow0+q16)*64 + g*8;
  v8s qa0=*(const v8s*)qp, qa1=*(const v8s*)(qp+32);

  v4f o[4]; v4f vz={0.f,0.f,0.f,0.f};
  #pragma unroll
  for(int dt=0;dt<4;++dt) o[dt]=vz;
  float zacc=0.f;
  v4f sc[32];

  // stage one 256-key half (kb2,hb2) into kbuf half hb2 (8 global_load_lds x 16B per thread)
  auto stage=[&](int kb2,int hb2){
    #pragma unroll
    for (int i=0;i<8;++i){
      int idx=i*256+tid, key=idx>>3, p=idx&7, pp=p^(key&7);
      const short* gp = kbase + (size_t)(kb2*512+hb2*256+key)*64 + pp*8;
      __builtin_amdgcn_global_load_lds((const __attribute__((address_space(1))) void*)gp,
          (__attribute__((address_space(3))) void*)((char*)kbuf + hb2*32768 + idx*16), 16, 0, 0);
    }
  };

#define QK_HALF(BUFOFF, SCOFF)                                          \
    _Pragma("unroll")                                                   \
    for (int t2=0;t2<16;++t2){                                          \
      int krow=t2*16+q16;                                               \
      int s0=g^(krow&7), s1=(g+4)^(krow&7);                             \
      v8s k0=*(const v8s*)&kbuf[BUFOFF+(krow*8+s0)*8];                  \
      v8s k1=*(const v8s*)&kbuf[BUFOFF+(krow*8+s1)*8];                  \
      v4f t=mfma16(k0,qa0,vz);                                          \
      sc[SCOFF+t2]=mfma16(k1,qa1,t);                                    \
    }

  stage(0,0);
  for (int kb=0; kb<=qb; ++kb){
    // ---- half 0 ----
    stage(kb,1);                                  // prefetch half 1 (buf1)
    asm volatile("s_waitcnt vmcnt(8)" ::: "memory");   // half 0 landed
    __builtin_amdgcn_s_barrier();
    asm volatile("" ::: "memory");
    QK_HALF(0, 0)
    __builtin_amdgcn_s_barrier();                 // all waves done reading buf0
    asm volatile("" ::: "memory");
    // ---- half 1 ----
    if (kb<qb){ stage(kb+1,0); asm volatile("s_waitcnt vmcnt(8)" ::: "memory"); }
    else      {                asm volatile("s_waitcnt vmcnt(0)" ::: "memory"); }
    __builtin_amdgcn_s_barrier();
    asm volatile("" ::: "memory");
    QK_HALF(16384, 16)
    __builtin_amdgcn_s_barrier();                 // all waves done reading buf1
    asm volatile("" ::: "memory");

    // ---- scale + causal mask (diag only) + first (block) softmax, all per-lane ----
    const bool diag = (kb==qb);
    float m1a[4]={-3e38f,-3e38f,-3e38f,-3e38f};
    #pragma unroll
    for (int ct=0;ct<32;++ct)
      #pragma unroll
      for (int r=0;r<4;++r){
        float s=sc[ct][r]*0.125f;
        if (diag && (qb*512+ct*16+g*4+r > qglob)) s=-1e38f;
        sc[ct][r]=s;
        m1a[r]=fmaxf(m1a[r],s);
      }
    float m1=fmaxf(fmaxf(m1a[0],m1a[1]),fmaxf(m1a[2],m1a[3]));
    m1=fmaxf(m1,__shfl_xor(m1,16)); m1=fmaxf(m1,__shfl_xor(m1,32));
    float d1a[4]={0.f,0.f,0.f,0.f};
    #pragma unroll
    for (int ct=0;ct<32;++ct)
      #pragma unroll
      for (int r=0;r<4;++r){
        float e=__expf(sc[ct][r]-m1);
        sc[ct][r]=e;
        d1a[r]+=e;
      }
    float d1=(d1a[0]+d1a[1])+(d1a[2]+d1a[3]);
    d1+=__shfl_xor(d1,16); d1+=__shfl_xor(d1,32);
    float d1inv=1.0f/d1;
    // ---- PV: w = exp(p1)-1; permuted-V layout -> A-fragment is lane-local ----
    #pragma unroll
    for (int c=0;c<16;++c){
      float wA[4], wB[4];
      #pragma unroll
      for (int r=0;r<4;++r){
        wA[r]=__expf(sc[2*c  ][r]*d1inv)-1.0f;
        wB[r]=__expf(sc[2*c+1][r]*d1inv)-1.0f;
        zacc+=wA[r]+wB[r];
      }
      union { v4u u; v8s s; } pa;
      pa.u[0]=pk2(wA[0],wA[1]); pa.u[1]=pk2(wA[2],wA[3]);
      pa.u[2]=pk2(wB[0],wB[1]); pa.u[3]=pk2(wB[2],wB[3]);
      const short* vfp = vf + ((((size_t)bh*4+kb)*16+c)*4)*512 + l*8;
      #pragma unroll
      for (int dt=0;dt<4;++dt){
        v8s vfr=*(const v8s*)(vfp + (size_t)dt*512);
        o[dt]=mfma16(pa.s,vfr,o[dt]);
      }
    }
  }
#undef QK_HALF
  // ---- epilogue: Z per q-row, baseline = total V sum (weight 1), Z base 2048 ----
  float z=zacc;
  z+=__shfl_xor(z,16); z+=__shfl_xor(z,32);
  float base[4];
  #pragma unroll
  for (int dt=0;dt<4;++dt){
    float s=0.f;
    #pragma unroll
    for (int kk=0;kk<4;++kk) s+=vbp[(size_t)(bh*4+kk)*64 + dt*16 + q16];
    base[dt]=s;
  }
  #pragma unroll
  for (int r=0;r<4;++r){
    float zr=__shfl(z, g*4+r);
    float inv=1.0f/(2048.0f+zr);
    int rowi=qrow0+g*4+r;
    size_t obase=((size_t)b*2048+rowi)*1024 + h*64;
    #pragma unroll
    for (int dt=0;dt<4;++dt)
      attn[obase + dt*16 + q16] = f2bf((o[dt][r]+base[dt])*inv);
  }
}

// ---------------- output projection (A bf16, B fp32 on-the-fly, out fp32) ----------------
__global__ __launch_bounds__(256) void oproj_gemm(const short* __restrict__ at,
    const float* __restrict__ Wo, const float* __restrict__ bo, float* __restrict__ out)
{
  __shared__ short As[4096], Bs[4096];
  const int tid=threadIdx.x, l=tid&63, w=tid>>6;
  const int bcol0=blockIdx.x*128, brow0=blockIdx.y*128;
  v4f acc[4][4];
  v4f vz={0.f,0.f,0.f,0.f};
  #pragma unroll
  for(int m=0;m<4;++m)
    #pragma unroll
    for(int n=0;n<4;++n) acc[m][n]=vz;
  gemm_core<1>(at, Wo, brow0, bcol0, tid, As, Bs, acc);
  const int wr=(w>>1)*64, wc=(w&1)*64;
  #pragma unroll
  for(int m=0;m<4;++m)
  #pragma unroll
  for(int n=0;n<4;++n)
  #pragma unroll
  for(int r=0;r<4;++r){
    int row=brow0+wr+m*16+(l>>4)*4+r;
    int col=bcol0+wc+n*16+(l&15);
    out[(size_t)row*1024+col]=acc[m][n][r]+bo[col];
  }
}

extern "C" void kernel_launch(void* const* d_in, const int* in_sizes, int n_in,
                              void* d_out, int out_size, void* d_ws, size_t ws_size,
                              hipStream_t stream)
{
  const float* x  =(const float*)d_in[0];
  const float* Wq =(const float*)d_in[1];
  const float* bq =(const float*)d_in[2];
  const float* Wk =(const float*)d_in[3];
  const float* bk =(const float*)d_in[4];
  const float* Wv =(const float*)d_in[5];
  const float* bv =(const float*)d_in[6];
  const float* Wo =(const float*)d_in[7];
  const float* bo =(const float*)d_in[8];
  float* out=(float*)d_out;
  char* ws=(char*)d_ws;
  // ws (32 MiB): [0,8M)=xb then at_ws (disjoint lifetimes); [8M)=q; [16M)=k; [24M)=vf.
  // d_out doubles as scratch until oproj overwrites it:
  //   [0,2M)=wqb, [2M,4M)=wkb, [4M,6M)=wvb (bf16), [7M)=vbp (fp32, 32KB).
  short* xb_ws =(short*)(ws);
  short* at_ws =(short*)(ws);
  short* q_ws  =(short*)(ws + ((size_t)8<<20));
  short* k_ws  =(short*)(ws + ((size_t)16<<20));
  short* vf_ws =(short*)(ws + ((size_t)24<<20));
  char*  outb  =(char*)d_out;
  short* wqb   =(short*)(outb);
  short* wkb   =(short*)(outb + ((size_t)2<<20));
  short* wvb   =(short*)(outb + ((size_t)4<<20));
  float* vbp_ws=(float*)(outb + ((size_t)7<<20));

  convert_kernel<<<dim3(7168),256,0,stream>>>(x,Wq,Wk,Wv,xb_ws,wqb,wkb,wvb);
  qkv_gemm<<<dim3(24,32),256,0,stream>>>(xb_ws,wqb,wkb,wvb,bq,bk,bv,q_ws,k_ws,vf_ws);
  vbsum_kernel<<<dim3(32,4),64,0,stream>>>(vf_ws,vbp_ws);
  attn_kernel<<<dim3(32,32),256,0,stream>>>(q_ws,k_ws,vf_ws,vbp_ws,at_ws);
  oproj_gemm<<<dim3(8,32),256,0,stream>>>(at_ws,Wo,bo,out);
}